// Round 2
// 318.597 us; speedup vs baseline: 1.3593x; 1.3593x over previous
//
#include <hip/hip_runtime.h>

#define DEVI __device__ __forceinline__

static constexpr float KEPS = 1e-8f;

DEVI float frcp(float x) { return __builtin_amdgcn_rcpf(x); }
DEVI float frsq(float x) { return __builtin_amdgcn_rsqf(x); }

// One Jacobi rotation on symmetric 4x4 A (indices P<Q), accumulating into V.
template<int P, int Q>
DEVI void jrot(float A[4][4], float V[4][4]) {
  float apq = A[P][Q];
  if (fabsf(apq) > 1e-20f) {
    float theta = (A[Q][Q] - A[P][P]) * 0.5f * frcp(apq);
    float t = copysignf(frcp(fabsf(theta) + sqrtf(theta * theta + 1.0f)), theta);
    float c = frsq(t * t + 1.0f);
    float s = t * c;
#pragma unroll
    for (int k = 0; k < 4; ++k) { float u = A[k][P], v = A[k][Q]; A[k][P] = c*u - s*v; A[k][Q] = s*u + c*v; }
#pragma unroll
    for (int k = 0; k < 4; ++k) { float u = A[P][k], v = A[Q][k]; A[P][k] = c*u - s*v; A[Q][k] = s*u + c*v; }
#pragma unroll
    for (int k = 0; k < 4; ++k) { float u = V[k][P], v = V[k][Q]; V[k][P] = c*u - s*v; V[k][Q] = s*u + c*v; }
  }
}

// Rotate child joint C about pivot (px,py,pz) by r.
template<int C>
DEVI void rotc(float t[21][3], float px, float py, float pz,
               float r00, float r01, float r02,
               float r10, float r11, float r12,
               float r20, float r21, float r22) {
  float x = t[C][0] - px, y = t[C][1] - py, z = t[C][2] - pz;
  t[C][0] = r00*x + r01*y + r02*z + px;
  t[C][1] = r10*x + r11*y + r12*z + py;
  t[C][2] = r20*x + r21*y + r22*z + pz;
}

// One twist step: align bone (PI -> I) toward target g[I]-t[PI]; rotate NC children.
template<int PI, int I, int C0, int C1, int C2, int NC>
DEVI void bone(float t[21][3], const float g[21][3]) {
  float px = t[PI][0], py = t[PI][1], pz = t[PI][2];
  float v0x = t[I][0] - px, v0y = t[I][1] - py, v0z = t[I][2] - pz;
  float v1x = g[I][0] - px, v1y = g[I][1] - py, v1z = g[I][2] - pz;
  float in0 = frcp(sqrtf(v0x*v0x + v0y*v0y + v0z*v0z) + KEPS);
  float in1 = frcp(sqrtf(v1x*v1x + v1y*v1y + v1z*v1z) + KEPS);
  float ax = v0x*in0, ay = v0y*in0, az = v0z*in0;
  float bx = v1x*in1, by = v1y*in1, bz = v1z*in1;
  float c = ax*bx + ay*by + az*bz;
  float cx = ay*bz - az*by;
  float cy = az*bx - ax*bz;
  float cz = ax*by - ay*bx;
  float s = sqrtf(cx*cx + cy*cy + cz*cz);
  float is = frcp(s + KEPS);
  float kx = cx*is, ky = cy*is, kz = cz*is;
  float omc = 1.0f - c;
  float r00 = 1.0f - omc*(ky*ky + kz*kz);
  float r11 = 1.0f - omc*(kx*kx + kz*kz);
  float r22 = 1.0f - omc*(kx*kx + ky*ky);
  float kxy = omc*kx*ky, kxz = omc*kx*kz, kyz = omc*ky*kz;
  float skx = s*kx, sky = s*ky, skz = s*kz;
  float r01 = kxy - skz, r10 = kxy + skz;
  float r02 = kxz + sky, r20 = kxz - sky;
  float r12 = kyz - skx, r21 = kyz + skx;
  rotc<C0>(t, px, py, pz, r00, r01, r02, r10, r11, r12, r20, r21, r22);
  if constexpr (NC > 1) rotc<C1>(t, px, py, pz, r00, r01, r02, r10, r11, r12, r20, r21, r22);
  if constexpr (NC > 2) rotc<C2>(t, px, py, pz, r00, r01, r02, r10, r11, r12, r20, r21, r22);
}

// Finger chain: base joint B, B+1, B+2, tip T.
template<int B, int T>
DEVI void finger(float t[21][3], const float g[21][3]) {
  bone<B,     B + 1, B + 1, B + 2, T, 3>(t, g);
  bone<B + 1, B + 2, B + 2, T,     T, 2>(t, g);
  bone<B + 2, T,     T,     T,     T, 1>(t, g);
}

__global__ void __launch_bounds__(64)
kin_kernel(const float* __restrict__ joint_gt, const float* __restrict__ tempJ,
           float* __restrict__ out, int N) {
  __shared__ float lds[64 * 63];
  const int tid = threadIdx.x;
  const long long base = (long long)blockIdx.x * (64LL * 63);
  const long long total = (long long)N * 63;
  const bool fullblk = (base + 64LL * 63) <= total;

  float t[21][3], g[21][3];

  // ---- stage tempJ (coalesced float4) -> LDS -> registers ----
  if (fullblk) {
    const float4* s4 = (const float4*)(tempJ + base);
#pragma unroll
    for (int it = 0; it < 16; ++it) { int i = it * 64 + tid; if (i < 1008) ((float4*)lds)[i] = s4[i]; }
  } else {
    for (int i = tid; i < 64 * 63; i += 64) { long long gi = base + i; lds[i] = (gi < total) ? tempJ[gi] : 0.0f; }
  }
  __syncthreads();
  {
    float rx = lds[tid * 63 + 0], ry = lds[tid * 63 + 1], rz = lds[tid * 63 + 2];
#pragma unroll
    for (int j = 0; j < 21; ++j) {
      t[j][0] = lds[tid * 63 + 3 * j + 0] - rx;
      t[j][1] = lds[tid * 63 + 3 * j + 1] - ry;
      t[j][2] = lds[tid * 63 + 3 * j + 2] - rz;
    }
  }
  __syncthreads();

  // ---- stage joint_gt ----
  if (fullblk) {
    const float4* s4 = (const float4*)(joint_gt + base);
#pragma unroll
    for (int it = 0; it < 16; ++it) { int i = it * 64 + tid; if (i < 1008) ((float4*)lds)[i] = s4[i]; }
  } else {
    for (int i = tid; i < 64 * 63; i += 64) { long long gi = base + i; lds[i] = (gi < total) ? joint_gt[gi] : 0.0f; }
  }
  __syncthreads();
  float wx = lds[tid * 63 + 0], wy = lds[tid * 63 + 1], wz = lds[tid * 63 + 2];
#pragma unroll
  for (int j = 0; j < 21; ++j) {
    g[j][0] = lds[tid * 63 + 3 * j + 0] - wx;
    g[j][1] = lds[tid * 63 + 3 * j + 1] - wy;
    g[j][2] = lds[tid * 63 + 3 * j + 2] - wz;
  }
  __syncthreads();

  // ---- H = tJ0^T @ jg (3x3 correlation) ----
  float H[3][3] = {{0, 0, 0}, {0, 0, 0}, {0, 0, 0}};
#pragma unroll
  for (int j = 0; j < 21; ++j)
#pragma unroll
    for (int a = 0; a < 3; ++a)
#pragma unroll
      for (int b = 0; b < 3; ++b)
        H[a][b] += t[j][a] * g[j][b];

  // ---- Horn's 4x4 N matrix; Jacobi eigensolver; max-eigenvector quaternion ----
  float Sxx = H[0][0], Sxy = H[0][1], Sxz = H[0][2];
  float Syx = H[1][0], Syy = H[1][1], Syz = H[1][2];
  float Szx = H[2][0], Szy = H[2][1], Szz = H[2][2];
  float A[4][4] = {
    {  Sxx + Syy + Szz, Syz - Szy,        Szx - Sxz,        Sxy - Syx },
    {  Syz - Szy,       Sxx - Syy - Szz,  Sxy + Syx,        Szx + Sxz },
    {  Szx - Sxz,       Sxy + Syx,       -Sxx + Syy - Szz,  Syz + Szy },
    {  Sxy - Syx,       Szx + Sxz,        Syz + Szy,       -Sxx - Syy + Szz }};
  float V[4][4] = {{1,0,0,0},{0,1,0,0},{0,0,1,0},{0,0,0,1}};
  // NOTE: unroll 1 — the sweep index touches no array, so A/V stay in VGPRs,
  // but the eigensolver's code footprint drops 6x (I$ fit: whole kernel ~21 KB < 32 KB).
#pragma unroll 1
  for (int sw = 0; sw < 6; ++sw) {
    jrot<0,1>(A, V); jrot<0,2>(A, V); jrot<0,3>(A, V);
    jrot<1,2>(A, V); jrot<1,3>(A, V); jrot<2,3>(A, V);
  }
  float e  = A[0][0];
  float qw = V[0][0], qx = V[1][0], qy = V[2][0], qz = V[3][0];
#define PICK(K) { bool bb = A[K][K] > e; e = bb ? A[K][K] : e; \
  qw = bb ? V[0][K] : qw; qx = bb ? V[1][K] : qx; qy = bb ? V[2][K] : qy; qz = bb ? V[3][K] : qz; }
  PICK(1) PICK(2) PICK(3)
#undef PICK
  float qn = frsq(qw*qw + qx*qx + qy*qy + qz*qz);
  qw *= qn; qx *= qn; qy *= qn; qz *= qn;
  float R00 = 1.0f - 2.0f*(qy*qy + qz*qz), R01 = 2.0f*(qx*qy - qw*qz), R02 = 2.0f*(qx*qz + qw*qy);
  float R10 = 2.0f*(qx*qy + qw*qz), R11 = 1.0f - 2.0f*(qx*qx + qz*qz), R12 = 2.0f*(qy*qz - qw*qx);
  float R20 = 2.0f*(qx*qz - qw*qy), R21 = 2.0f*(qy*qz + qw*qx), R22 = 1.0f - 2.0f*(qx*qx + qy*qy);

  // ---- tJ = Rw @ tJ0 ----
#pragma unroll
  for (int j = 1; j < 21; ++j) {
    float x = t[j][0], y = t[j][1], z = t[j][2];
    t[j][0] = R00*x + R01*y + R02*z;
    t[j][1] = R10*x + R11*y + R12*z;
    t[j][2] = R20*x + R21*y + R22*z;
  }

  // ---- 15 twist alignments (output == final tJ; FK is algebraically identical) ----
  finger<1, 17>(t, g);
  finger<4, 18>(t, g);
  finger<7, 20>(t, g);
  finger<10, 19>(t, g);
  finger<13, 16>(t, g);

  // ---- registers -> LDS -> coalesced float4 store (+ wrist) ----
#pragma unroll
  for (int j = 0; j < 21; ++j) {
    lds[tid * 63 + 3 * j + 0] = t[j][0] + wx;
    lds[tid * 63 + 3 * j + 1] = t[j][1] + wy;
    lds[tid * 63 + 3 * j + 2] = t[j][2] + wz;
  }
  __syncthreads();
  if (fullblk) {
    float4* d4 = (float4*)(out + base);
#pragma unroll
    for (int it = 0; it < 16; ++it) { int i = it * 64 + tid; if (i < 1008) d4[i] = ((const float4*)lds)[i]; }
  } else {
    for (int i = tid; i < 64 * 63; i += 64) { long long gi = base + i; if (gi < total) out[gi] = lds[i]; }
  }
}

extern "C" void kernel_launch(void* const* d_in, const int* in_sizes, int n_in,
                              void* d_out, int out_size, void* d_ws, size_t ws_size,
                              hipStream_t stream) {
  const float* joint_gt = (const float*)d_in[0];
  const float* tempJ    = (const float*)d_in[1];
  float* out = (float*)d_out;
  int N = in_sizes[0] / 63;
  int blocks = (N + 63) / 64;
  hipLaunchKernelGGL(kin_kernel, dim3(blocks), dim3(64), 0, stream,
                     joint_gt, tempJ, out, N);
}